// Round 14
// baseline (296.593 us; speedup 1.0000x reference)
//
#include <hip/hip_runtime.h>
#include <hip/hip_bf16.h>

#define N_NODES 100000
#define N_EDGES 1600000

// partition geometry
#define BIN_SHIFT 9
#define NBIN 196                 // ceil(100000 / 512)
#define NBLK 256                 // partition blocks
#define CHUNK 6250               // N_EDGES / NBLK (exact)
#define SCAN_N (NBIN * NBLK)     // 50176
#define GEMM_BLKS 782            // ceil(100000 / 128)

typedef __attribute__((ext_vector_type(8))) short bf16x8;
typedef __attribute__((ext_vector_type(4))) float f32x4;

__device__ inline unsigned short f2bf(float f) {
    union { float f; unsigned u; } v; v.f = f;
    unsigned r = v.u + 0x7FFF + ((v.u >> 16) & 1);   // RNE
    return (unsigned short)(r >> 16);
}
__device__ inline float bf2f(unsigned short h) {
    union { unsigned u; float f; } v; v.u = ((unsigned)h) << 16;
    return v.f;
}

// ---------------- P1: per-block bin histogram ----------------

__global__ __launch_bounds__(256) void p1_bincnt(const int* __restrict__ row,
                                                 int* __restrict__ cnt) {
    __shared__ int h[NBIN];
    for (int i = threadIdx.x; i < NBIN; i += 256) h[i] = 0;
    __syncthreads();
    int base = blockIdx.x * CHUNK;
    int end = base + CHUNK; if (end > N_EDGES) end = N_EDGES;
    for (int i = base + threadIdx.x; i < end; i += 256)
        atomicAdd(&h[row[i] >> BIN_SHIFT], 1);
    __syncthreads();
    for (int b = threadIdx.x; b < NBIN; b += 256)
        cnt[b * NBLK + blockIdx.x] = h[b];
}

// ---------------- P2 (block 0) + weight pack (blocks 1..40) ----------------
// pack: Bp[((nt*4 + kb)*64 + lane)*8 + j] = bf16(W[kb*32 + (lane>>4)*8 + j][nt*16 + (lane&15)])

__global__ __launch_bounds__(1024) void p2_scan_pack(const int* __restrict__ cnt,
                                                     int* __restrict__ base,
                                                     int* __restrict__ rp,
                                                     const float* __restrict__ W0,
                                                     const float* __restrict__ W1,
                                                     const float* __restrict__ W2,
                                                     unsigned short* __restrict__ Bp0,
                                                     unsigned short* __restrict__ Bp1,
                                                     unsigned short* __restrict__ Bp2) {
    if (blockIdx.x == 0) {
        __shared__ int s[1024];
        int t = threadIdx.x;
        const int per = SCAN_N / 1024;   // 49, exact
        int lo = t * per, hi = lo + per;
        int sum = 0;
        for (int i = lo; i < hi; ++i) sum += cnt[i];
        s[t] = sum;
        __syncthreads();
        for (int off = 1; off < 1024; off <<= 1) {
            int v = (t >= off) ? s[t - off] : 0;
            __syncthreads();
            s[t] += v;
            __syncthreads();
        }
        int run = s[t] - sum;   // exclusive prefix
        for (int i = lo; i < hi; ++i) { int c = cnt[i]; base[i] = run; run += c; }
        if (t == 0) rp[N_NODES] = N_EDGES;
    } else {
        int idx = (blockIdx.x - 1) * 1024 + threadIdx.x;   // < 40960
        const float* W; unsigned short* Bp; int fout, li;
        if (idx < 16384)      { W = W0; Bp = Bp0; fout = 128; li = idx; }
        else if (idx < 32768) { W = W1; Bp = Bp1; fout = 128; li = idx - 16384; }
        else                  { W = W2; Bp = Bp2; fout = 64;  li = idx - 32768; }
        int j = li & 7, lane = (li >> 3) & 63, kb = (li >> 9) & 3, nt = li >> 11;
        int k = kb * 32 + (lane >> 4) * 8 + j;
        int col = nt * 16 + (lane & 15);
        Bp[li] = f2bf(W[k * fout + col]);
    }
}

// ---------------- P3: partition edges into (block,bin)-private runs ----------------

__global__ __launch_bounds__(256) void p3_partition(const int* __restrict__ row,
                                                    const int* __restrict__ col,
                                                    const float* __restrict__ val,
                                                    const int* __restrict__ base,
                                                    int2* __restrict__ bout) {
    __shared__ int cur[NBIN];
    for (int i = threadIdx.x; i < NBIN; i += 256)
        cur[i] = base[i * NBLK + blockIdx.x];
    __syncthreads();
    int lo = blockIdx.x * CHUNK;
    int end = lo + CHUNK; if (end > N_EDGES) end = N_EDGES;
    for (int i = lo + threadIdx.x; i < end; i += 256) {
        int r = row[i];
        int b = r >> BIN_SHIFT;
        int p = atomicAdd(&cur[b], 1);
        int2 rec;
        rec.x = col[i] | ((r & 511) << 17);
        rec.y = __float_as_int(val[i]);
        bout[p] = rec;
    }
}

// P4: one block per bin; emits rp and 4-byte edge records:
// erec = col<<15 | (bf16(val) & 0x7FFF). val is uniform[0,1) -> sign bit 0 -> LOSSLESS.

__global__ __launch_bounds__(256) void p4_binscatter(const int* __restrict__ base,
                                                     const int2* __restrict__ bin_in,
                                                     int* __restrict__ rp,
                                                     unsigned* __restrict__ erec) {
    __shared__ int cnt[512];
    __shared__ int part[256];
    const int b = blockIdx.x;
    const int t = threadIdx.x;
    const int lo = base[b * NBLK];
    const int hi = (b + 1 < NBIN) ? base[(b + 1) * NBLK] : N_EDGES;

    cnt[t] = 0; cnt[t + 256] = 0;
    __syncthreads();
    for (int e = lo + t; e < hi; e += 256)
        atomicAdd(&cnt[(unsigned)bin_in[e].x >> 17], 1);
    __syncthreads();

    int s0 = cnt[2 * t], s1 = cnt[2 * t + 1];
    int tsum = s0 + s1;
    part[t] = tsum;
    __syncthreads();
    for (int off = 1; off < 256; off <<= 1) {
        int v = (t >= off) ? part[t - off] : 0;
        __syncthreads();
        part[t] += v;
        __syncthreads();
    }
    int run = part[t] - tsum;
    cnt[2 * t] = run;
    cnt[2 * t + 1] = run + s0;

    const int rowbase = b << BIN_SHIFT;
    int r0 = rowbase + 2 * t, r1 = rowbase + 2 * t + 1;
    if (r0 < N_NODES) rp[r0] = lo + run;
    if (r1 < N_NODES) rp[r1] = lo + run + s0;
    __syncthreads();

    for (int e = lo + t; e < hi; e += 256) {
        int2 q = bin_in[e];
        int rl = (unsigned)q.x >> 17;
        int p = lo + atomicAdd(&cnt[rl], 1);
        unsigned c = (unsigned)(q.x & 0x1FFFF);
        erec[p] = (c << 15) | ((unsigned)f2bf(__int_as_float(q.y)) & 0x7FFFu);
    }
}

// ---------------- GEMM: Y[n][NT*16](bf16) = X[n][128] @ W + bias ----------------
// One block covers 128 rows x FULL output width (A read once).

template<int NT, bool AF32>
__global__ __launch_bounds__(256) void gemm_mfma(const void* __restrict__ Xv,
                                                 const unsigned short* __restrict__ Bp,
                                                 const float* __restrict__ bias,
                                                 unsigned short* __restrict__ Y, int n) {
    constexpr int FOUT = NT * 16;
    const int wave = threadIdx.x >> 6;
    const int lane = threadIdx.x & 63;
    const int l15 = lane & 15, kg = lane >> 4;
    const int rowTile = blockIdx.x * 128 + wave * 32;

    int r0 = rowTile + l15;      if (r0 >= n) r0 = n - 1;
    int r1 = rowTile + 16 + l15; if (r1 >= n) r1 = n - 1;

    bf16x8 a0[4], a1[4];
    if constexpr (AF32) {
        const float* x0 = (const float*)Xv + (size_t)r0 * 128 + kg * 8;
        const float* x1 = (const float*)Xv + (size_t)r1 * 128 + kg * 8;
        #pragma unroll
        for (int kb = 0; kb < 4; ++kb) {
            float4 u = *reinterpret_cast<const float4*>(x0 + kb * 32);
            float4 v = *reinterpret_cast<const float4*>(x0 + kb * 32 + 4);
            a0[kb] = (bf16x8){(short)f2bf(u.x), (short)f2bf(u.y), (short)f2bf(u.z), (short)f2bf(u.w),
                              (short)f2bf(v.x), (short)f2bf(v.y), (short)f2bf(v.z), (short)f2bf(v.w)};
            float4 p = *reinterpret_cast<const float4*>(x1 + kb * 32);
            float4 q = *reinterpret_cast<const float4*>(x1 + kb * 32 + 4);
            a1[kb] = (bf16x8){(short)f2bf(p.x), (short)f2bf(p.y), (short)f2bf(p.z), (short)f2bf(p.w),
                              (short)f2bf(q.x), (short)f2bf(q.y), (short)f2bf(q.z), (short)f2bf(q.w)};
        }
    } else {
        const bf16x8* x0 = reinterpret_cast<const bf16x8*>((const unsigned short*)Xv + (size_t)r0 * 128 + kg * 8);
        const bf16x8* x1 = reinterpret_cast<const bf16x8*>((const unsigned short*)Xv + (size_t)r1 * 128 + kg * 8);
        #pragma unroll
        for (int kb = 0; kb < 4; ++kb) { a0[kb] = x0[kb * 4]; a1[kb] = x1[kb * 4]; }
    }

    f32x4 c0[NT], c1[NT];
    #pragma unroll
    for (int t = 0; t < NT; ++t) {
        c0[t] = (f32x4){0.f, 0.f, 0.f, 0.f};
        c1[t] = (f32x4){0.f, 0.f, 0.f, 0.f};
    }

    const bf16x8* bpv = reinterpret_cast<const bf16x8*>(Bp);
    #pragma unroll
    for (int nt = 0; nt < NT; ++nt) {
        const bf16x8* bp = bpv + (size_t)(nt * 4) * 64 + lane;
        #pragma unroll
        for (int kb = 0; kb < 4; ++kb) {
            bf16x8 b = bp[kb * 64];
            c0[nt] = __builtin_amdgcn_mfma_f32_16x16x32_bf16(a0[kb], b, c0[nt], 0, 0, 0);
            c1[nt] = __builtin_amdgcn_mfma_f32_16x16x32_bf16(a1[kb], b, c1[nt], 0, 0, 0);
        }
    }

    // C layout: col = lane&15, row = (lane>>4)*4 + j
    #pragma unroll
    for (int nt = 0; nt < NT; ++nt) {
        int col = nt * 16 + l15;
        float bv = bias[col];
        int rb = rowTile + kg * 4;
        #pragma unroll
        for (int j = 0; j < 4; ++j) {
            int ra = rb + j;
            if (ra < n) Y[(size_t)ra * FOUT + col] = f2bf(c0[nt][j] + bv);
            int rc = rb + 16 + j;
            if (rc < n) Y[(size_t)rc * FOUT + col] = f2bf(c1[nt][j] + bv);
        }
    }
}

// ---------------- SpMM mid: F=128, one wave/node, 8-deep readlane batches, 4B records ----

__global__ __launch_bounds__(256) void spmm_mid(const int* __restrict__ rp,
                                                const unsigned* __restrict__ erec,
                                                const unsigned* __restrict__ G,   // [n][64] u32 (128 bf16)
                                                unsigned* __restrict__ Y, int n) {
    int node = blockIdx.x * 4 + (threadIdx.x >> 6);
    if (node >= n) return;
    int lane = threadIdx.x & 63;
    int e0 = rp[node], e1 = rp[node + 1];
    float a0 = 0.f, a1 = 0.f;
    const unsigned* Gf = G + lane;
    while (e0 < e1) {
        int take = e1 - e0; if (take > 64) take = 64;
        unsigned rec = erec[e0 + (lane < take ? lane : take - 1)];
        int i = 0;
        for (; i + 8 <= take; i += 8) {
            unsigned g[8]; float v[8];
            #pragma unroll
            for (int j = 0; j < 8; ++j) {
                unsigned q = __builtin_amdgcn_readlane(rec, i + j);
                v[j] = __uint_as_float((q & 0x7FFFu) << 16);
                g[j] = Gf[(size_t)(q >> 15) * 64];
            }
            #pragma unroll
            for (int j = 0; j < 8; ++j) {
                a0 += v[j] * bf2f((unsigned short)g[j]);
                a1 += v[j] * bf2f((unsigned short)(g[j] >> 16));
            }
        }
        for (; i < take; ++i) {
            unsigned q = __builtin_amdgcn_readlane(rec, i);
            float v = __uint_as_float((q & 0x7FFFu) << 16);
            unsigned g = Gf[(size_t)(q >> 15) * 64];
            a0 += v * bf2f((unsigned short)g);
            a1 += v * bf2f((unsigned short)(g >> 16));
        }
        e0 += take;
    }
    a0 = fmaxf(a0, 0.f); a1 = fmaxf(a1, 0.f);
    Y[(size_t)node * 64 + lane] = (unsigned)f2bf(a0) | ((unsigned)f2bf(a1) << 16);
}

// ---------------- SpMM last: F=64, 8-lane x 16B groups, 8 edges per dwordx4 round, 4B records ----

__global__ __launch_bounds__(256) void spmm_last(const int* __restrict__ rp,
                                                 const unsigned* __restrict__ erec,
                                                 const unsigned short* __restrict__ G,  // [n][64] bf16
                                                 float* __restrict__ out, int n) {
    int node = blockIdx.x * 4 + (threadIdx.x >> 6);
    if (node >= n) return;
    int lane = threadIdx.x & 63;
    int eg = lane >> 3, fg = lane & 7;
    int e0 = rp[node], e1 = rp[node + 1];
    float acc[8] = {0.f, 0.f, 0.f, 0.f, 0.f, 0.f, 0.f, 0.f};
    while (e0 < e1) {
        int take = e1 - e0; if (take > 64) take = 64;
        unsigned rec = erec[e0 + (lane < take ? lane : take - 1)];
        for (int r = 0; r < take; r += 16) {
            uint4 d[2]; float vv[2];
            #pragma unroll
            for (int s = 0; s < 2; ++s) {
                int idx = r + s * 8 + eg;
                bool ok = idx < take;
                int src = ok ? idx : take - 1;
                unsigned q = __shfl(rec, src);
                float v = __uint_as_float((q & 0x7FFFu) << 16);
                vv[s] = ok ? v : 0.f;
                d[s] = *reinterpret_cast<const uint4*>(G + (size_t)(q >> 15) * 64 + fg * 8);
            }
            #pragma unroll
            for (int s = 0; s < 2; ++s) {
                unsigned w0 = d[s].x, w1 = d[s].y, w2 = d[s].z, w3 = d[s].w;
                acc[0] += vv[s] * bf2f((unsigned short)w0);
                acc[1] += vv[s] * bf2f((unsigned short)(w0 >> 16));
                acc[2] += vv[s] * bf2f((unsigned short)w1);
                acc[3] += vv[s] * bf2f((unsigned short)(w1 >> 16));
                acc[4] += vv[s] * bf2f((unsigned short)w2);
                acc[5] += vv[s] * bf2f((unsigned short)(w2 >> 16));
                acc[6] += vv[s] * bf2f((unsigned short)w3);
                acc[7] += vv[s] * bf2f((unsigned short)(w3 >> 16));
            }
        }
        e0 += take;
    }
    #pragma unroll
    for (int k = 0; k < 8; ++k) {
        acc[k] += __shfl_xor(acc[k], 8);
        acc[k] += __shfl_xor(acc[k], 16);
        acc[k] += __shfl_xor(acc[k], 32);
    }
    if (eg == 0) {
        float4 oA = {acc[0], acc[1], acc[2], acc[3]};
        float4 oB = {acc[4], acc[5], acc[6], acc[7]};
        float4* o = reinterpret_cast<float4*>(out + (size_t)node * 64 + fg * 8);
        o[0] = oA;
        o[1] = oB;
    }
}

// ---------------- launch ----------------

extern "C" void kernel_launch(void* const* d_in, const int* in_sizes, int n_in,
                              void* d_out, int out_size, void* d_ws, size_t ws_size,
                              hipStream_t stream) {
    const float* x    = (const float*)d_in[0];
    const int*   arow = (const int*)d_in[1];
    const int*   acol = (const int*)d_in[2];
    const float* aval = (const float*)d_in[3];
    const float* W0   = (const float*)d_in[4];
    const float* b0   = (const float*)d_in[5];
    const float* W1   = (const float*)d_in[6];
    const float* b1   = (const float*)d_in[7];
    const float* W2   = (const float*)d_in[8];
    const float* b2   = (const float*)d_in[9];
    float* out = (float*)d_out;

    // workspace layout
    unsigned short* hlin = (unsigned short*)d_ws;                       // N*128 u16
    unsigned short* hact = hlin + (size_t)N_NODES * 128;                // N*128 u16
    unsigned short* Bp0  = hact + (size_t)N_NODES * 128;                // 16384 u16
    unsigned short* Bp1  = Bp0 + 16384;                                 // 16384 u16
    unsigned short* Bp2  = Bp1 + 16384;                                 // 8192 u16
    int* cnt  = (int*)(Bp2 + 8192);                                     // SCAN_N
    int* base = cnt + SCAN_N;                                           // SCAN_N
    int* rp   = base + SCAN_N;                                          // N+2
    int2* bin_in = (int2*)(rp + N_NODES + 2);                           // E int2
    unsigned* erec = (unsigned*)(bin_in + N_EDGES);                     // E u32

    // partition / CSR build (pack rides in p2's launch; p3 kept high-occupancy, unfused)
    p1_bincnt<<<NBLK, 256, 0, stream>>>(arow, cnt);
    p2_scan_pack<<<41, 1024, 0, stream>>>(cnt, base, rp, W0, W1, W2, Bp0, Bp1, Bp2);
    p3_partition<<<NBLK, 256, 0, stream>>>(arow, acol, aval, base, bin_in);
    p4_binscatter<<<NBIN, 256, 0, stream>>>(base, bin_in, rp, erec);

    int spmm_grid = (N_NODES + 3) / 4;

    // layer 0 (x f32 -> bf16 cast fused into GEMM A-read)
    gemm_mfma<8, true><<<GEMM_BLKS, 256, 0, stream>>>(x, Bp0, b0, hlin, N_NODES);
    spmm_mid<<<spmm_grid, 256, 0, stream>>>(rp, erec, (const unsigned*)hlin, (unsigned*)hact, N_NODES);
    // layer 1
    gemm_mfma<8, false><<<GEMM_BLKS, 256, 0, stream>>>(hact, Bp1, b1, hlin, N_NODES);
    spmm_mid<<<spmm_grid, 256, 0, stream>>>(rp, erec, (const unsigned*)hlin, (unsigned*)hact, N_NODES);
    // layer 2
    gemm_mfma<4, false><<<GEMM_BLKS, 256, 0, stream>>>(hact, Bp2, b2, hlin, N_NODES);
    spmm_last<<<spmm_grid, 256, 0, stream>>>(rp, erec, hlin, out, N_NODES);
}

// Round 15
// 291.535 us; speedup vs baseline: 1.0173x; 1.0173x over previous
//
#include <hip/hip_runtime.h>
#include <hip/hip_bf16.h>

#define N_NODES 100000
#define N_EDGES 1600000

// partition geometry
#define BIN_SHIFT 9
#define NBIN 196                 // ceil(100000 / 512)
#define NBLK 256                 // partition blocks
#define CHUNK 6250               // N_EDGES / NBLK (exact)
#define SCAN_N (NBIN * NBLK)     // 50176
#define GEMM_BLKS 782            // ceil(100000 / 128)

typedef __attribute__((ext_vector_type(8))) short bf16x8;
typedef __attribute__((ext_vector_type(4))) float f32x4;

__device__ inline unsigned short f2bf(float f) {
    union { float f; unsigned u; } v; v.f = f;
    unsigned r = v.u + 0x7FFF + ((v.u >> 16) & 1);   // RNE
    return (unsigned short)(r >> 16);
}
__device__ inline float bf2f(unsigned short h) {
    union { unsigned u; float f; } v; v.u = ((unsigned)h) << 16;
    return v.f;
}

// ---------------- P1: per-block bin histogram ----------------

__global__ __launch_bounds__(256) void p1_bincnt(const int* __restrict__ row,
                                                 int* __restrict__ cnt) {
    __shared__ int h[NBIN];
    for (int i = threadIdx.x; i < NBIN; i += 256) h[i] = 0;
    __syncthreads();
    int base = blockIdx.x * CHUNK;
    int end = base + CHUNK; if (end > N_EDGES) end = N_EDGES;
    for (int i = base + threadIdx.x; i < end; i += 256)
        atomicAdd(&h[row[i] >> BIN_SHIFT], 1);
    __syncthreads();
    for (int b = threadIdx.x; b < NBIN; b += 256)
        cnt[b * NBLK + blockIdx.x] = h[b];
}

// ---------------- P2 (block 0) + weight pack (blocks 1..40) ----------------
// pack: Bp[((nt*4 + kb)*64 + lane)*8 + j] = bf16(W[kb*32 + (lane>>4)*8 + j][nt*16 + (lane&15)])

__global__ __launch_bounds__(1024) void p2_scan_pack(const int* __restrict__ cnt,
                                                     int* __restrict__ base,
                                                     int* __restrict__ rp,
                                                     const float* __restrict__ W0,
                                                     const float* __restrict__ W1,
                                                     const float* __restrict__ W2,
                                                     unsigned short* __restrict__ Bp0,
                                                     unsigned short* __restrict__ Bp1,
                                                     unsigned short* __restrict__ Bp2) {
    if (blockIdx.x == 0) {
        __shared__ int s[1024];
        int t = threadIdx.x;
        const int per = SCAN_N / 1024;   // 49, exact
        int lo = t * per, hi = lo + per;
        int sum = 0;
        for (int i = lo; i < hi; ++i) sum += cnt[i];
        s[t] = sum;
        __syncthreads();
        for (int off = 1; off < 1024; off <<= 1) {
            int v = (t >= off) ? s[t - off] : 0;
            __syncthreads();
            s[t] += v;
            __syncthreads();
        }
        int run = s[t] - sum;   // exclusive prefix
        for (int i = lo; i < hi; ++i) { int c = cnt[i]; base[i] = run; run += c; }
        if (t == 0) rp[N_NODES] = N_EDGES;
    } else {
        int idx = (blockIdx.x - 1) * 1024 + threadIdx.x;   // < 40960
        const float* W; unsigned short* Bp; int fout, li;
        if (idx < 16384)      { W = W0; Bp = Bp0; fout = 128; li = idx; }
        else if (idx < 32768) { W = W1; Bp = Bp1; fout = 128; li = idx - 16384; }
        else                  { W = W2; Bp = Bp2; fout = 64;  li = idx - 32768; }
        int j = li & 7, lane = (li >> 3) & 63, kb = (li >> 9) & 3, nt = li >> 11;
        int k = kb * 32 + (lane >> 4) * 8 + j;
        int col = nt * 16 + (lane & 15);
        Bp[li] = f2bf(W[k * fout + col]);
    }
}

// ---------------- GEMM body: Y[n][NT*16](bf16) = X[n][128] @ W + bias ----------------
// One block covers 128 rows x FULL output width (A read once).

template<int NT, bool AF32>
__device__ __forceinline__ void gemm_body(int bid, const void* __restrict__ Xv,
                                          const unsigned short* __restrict__ Bp,
                                          const float* __restrict__ bias,
                                          unsigned short* __restrict__ Y, int n) {
    constexpr int FOUT = NT * 16;
    const int wave = threadIdx.x >> 6;
    const int lane = threadIdx.x & 63;
    const int l15 = lane & 15, kg = lane >> 4;
    const int rowTile = bid * 128 + wave * 32;

    int r0 = rowTile + l15;      if (r0 >= n) r0 = n - 1;
    int r1 = rowTile + 16 + l15; if (r1 >= n) r1 = n - 1;

    bf16x8 a0[4], a1[4];
    if constexpr (AF32) {
        const float* x0 = (const float*)Xv + (size_t)r0 * 128 + kg * 8;
        const float* x1 = (const float*)Xv + (size_t)r1 * 128 + kg * 8;
        #pragma unroll
        for (int kb = 0; kb < 4; ++kb) {
            float4 u = *reinterpret_cast<const float4*>(x0 + kb * 32);
            float4 v = *reinterpret_cast<const float4*>(x0 + kb * 32 + 4);
            a0[kb] = (bf16x8){(short)f2bf(u.x), (short)f2bf(u.y), (short)f2bf(u.z), (short)f2bf(u.w),
                              (short)f2bf(v.x), (short)f2bf(v.y), (short)f2bf(v.z), (short)f2bf(v.w)};
            float4 p = *reinterpret_cast<const float4*>(x1 + kb * 32);
            float4 q = *reinterpret_cast<const float4*>(x1 + kb * 32 + 4);
            a1[kb] = (bf16x8){(short)f2bf(p.x), (short)f2bf(p.y), (short)f2bf(p.z), (short)f2bf(p.w),
                              (short)f2bf(q.x), (short)f2bf(q.y), (short)f2bf(q.z), (short)f2bf(q.w)};
        }
    } else {
        const bf16x8* x0 = reinterpret_cast<const bf16x8*>((const unsigned short*)Xv + (size_t)r0 * 128 + kg * 8);
        const bf16x8* x1 = reinterpret_cast<const bf16x8*>((const unsigned short*)Xv + (size_t)r1 * 128 + kg * 8);
        #pragma unroll
        for (int kb = 0; kb < 4; ++kb) { a0[kb] = x0[kb * 4]; a1[kb] = x1[kb * 4]; }
    }

    f32x4 c0[NT], c1[NT];
    #pragma unroll
    for (int t = 0; t < NT; ++t) {
        c0[t] = (f32x4){0.f, 0.f, 0.f, 0.f};
        c1[t] = (f32x4){0.f, 0.f, 0.f, 0.f};
    }

    const bf16x8* bpv = reinterpret_cast<const bf16x8*>(Bp);
    #pragma unroll
    for (int nt = 0; nt < NT; ++nt) {
        const bf16x8* bp = bpv + (size_t)(nt * 4) * 64 + lane;
        #pragma unroll
        for (int kb = 0; kb < 4; ++kb) {
            bf16x8 b = bp[kb * 64];
            c0[nt] = __builtin_amdgcn_mfma_f32_16x16x32_bf16(a0[kb], b, c0[nt], 0, 0, 0);
            c1[nt] = __builtin_amdgcn_mfma_f32_16x16x32_bf16(a1[kb], b, c1[nt], 0, 0, 0);
        }
    }

    // C layout: col = lane&15, row = (lane>>4)*4 + j
    #pragma unroll
    for (int nt = 0; nt < NT; ++nt) {
        int col = nt * 16 + l15;
        float bv = bias[col];
        int rb = rowTile + kg * 4;
        #pragma unroll
        for (int j = 0; j < 4; ++j) {
            int ra = rb + j;
            if (ra < n) Y[(size_t)ra * FOUT + col] = f2bf(c0[nt][j] + bv);
            int rc = rb + 16 + j;
            if (rc < n) Y[(size_t)rc * FOUT + col] = f2bf(c1[nt][j] + bv);
        }
    }
}

template<int NT, bool AF32>
__global__ __launch_bounds__(256) void gemm_mfma(const void* __restrict__ Xv,
                                                 const unsigned short* __restrict__ Bp,
                                                 const float* __restrict__ bias,
                                                 unsigned short* __restrict__ Y, int n) {
    gemm_body<NT, AF32>(blockIdx.x, Xv, Bp, bias, Y, n);
}

// ---------------- P3 partition (blocks 0..255) + layer-0 GEMM (blocks 256..1037) ----------
// Both depend only on p2 (p3 on `base`, gemm0 on Bp0 packed in p2's launch).
// Occupancy coupling (92 VGPR charged to p3 blocks) costs less than serializing:
// measured R12 291.9 us (fused) vs R13 296.6 us (split).

__global__ __launch_bounds__(256) void p3_gemm0(const int* __restrict__ row,
                                                const int* __restrict__ col,
                                                const float* __restrict__ val,
                                                const int* __restrict__ base,
                                                int2* __restrict__ bout,
                                                const float* __restrict__ x,
                                                const unsigned short* __restrict__ Bp0,
                                                const float* __restrict__ b0,
                                                unsigned short* __restrict__ hlin, int n) {
    if (blockIdx.x < NBLK) {
        __shared__ int cur[NBIN];
        for (int i = threadIdx.x; i < NBIN; i += 256)
            cur[i] = base[i * NBLK + blockIdx.x];
        __syncthreads();
        int lo = blockIdx.x * CHUNK;
        int end = lo + CHUNK; if (end > N_EDGES) end = N_EDGES;
        for (int i = lo + threadIdx.x; i < end; i += 256) {
            int r = row[i];
            int b = r >> BIN_SHIFT;
            int p = atomicAdd(&cur[b], 1);
            int2 rec;
            rec.x = col[i] | ((r & 511) << 17);
            rec.y = __float_as_int(val[i]);
            bout[p] = rec;
        }
    } else {
        gemm_body<8, true>(blockIdx.x - NBLK, x, Bp0, b0, hlin, n);
    }
}

// P4: one block per bin; emits rp and 4-byte edge records:
// erec = col<<15 | (bf16(val) & 0x7FFF). val is uniform[0,1) -> sign bit 0 -> LOSSLESS.

__global__ __launch_bounds__(256) void p4_binscatter(const int* __restrict__ base,
                                                     const int2* __restrict__ bin_in,
                                                     int* __restrict__ rp,
                                                     unsigned* __restrict__ erec) {
    __shared__ int cnt[512];
    __shared__ int part[256];
    const int b = blockIdx.x;
    const int t = threadIdx.x;
    const int lo = base[b * NBLK];
    const int hi = (b + 1 < NBIN) ? base[(b + 1) * NBLK] : N_EDGES;

    cnt[t] = 0; cnt[t + 256] = 0;
    __syncthreads();
    for (int e = lo + t; e < hi; e += 256)
        atomicAdd(&cnt[(unsigned)bin_in[e].x >> 17], 1);
    __syncthreads();

    int s0 = cnt[2 * t], s1 = cnt[2 * t + 1];
    int tsum = s0 + s1;
    part[t] = tsum;
    __syncthreads();
    for (int off = 1; off < 256; off <<= 1) {
        int v = (t >= off) ? part[t - off] : 0;
        __syncthreads();
        part[t] += v;
        __syncthreads();
    }
    int run = part[t] - tsum;
    cnt[2 * t] = run;
    cnt[2 * t + 1] = run + s0;

    const int rowbase = b << BIN_SHIFT;
    int r0 = rowbase + 2 * t, r1 = rowbase + 2 * t + 1;
    if (r0 < N_NODES) rp[r0] = lo + run;
    if (r1 < N_NODES) rp[r1] = lo + run + s0;
    __syncthreads();

    for (int e = lo + t; e < hi; e += 256) {
        int2 q = bin_in[e];
        int rl = (unsigned)q.x >> 17;
        int p = lo + atomicAdd(&cnt[rl], 1);
        unsigned c = (unsigned)(q.x & 0x1FFFF);
        erec[p] = (c << 15) | ((unsigned)f2bf(__int_as_float(q.y)) & 0x7FFFu);
    }
}

// ---------------- SpMM mid: F=128, one wave/node, 8-deep readlane batches, 4B records ----
// At the measured structural floor: FETCH ~177MB @ ~3.0-3.5 TB/s random-gather service
// rate, invariant across 8 structural variants (R3-R11). MLP beyond 8-deep: no gain (R8).

__global__ __launch_bounds__(256) void spmm_mid(const int* __restrict__ rp,
                                                const unsigned* __restrict__ erec,
                                                const unsigned* __restrict__ G,   // [n][64] u32 (128 bf16)
                                                unsigned* __restrict__ Y, int n) {
    int node = blockIdx.x * 4 + (threadIdx.x >> 6);
    if (node >= n) return;
    int lane = threadIdx.x & 63;
    int e0 = rp[node], e1 = rp[node + 1];
    float a0 = 0.f, a1 = 0.f;
    const unsigned* Gf = G + lane;
    while (e0 < e1) {
        int take = e1 - e0; if (take > 64) take = 64;
        unsigned rec = erec[e0 + (lane < take ? lane : take - 1)];
        int i = 0;
        for (; i + 8 <= take; i += 8) {
            unsigned g[8]; float v[8];
            #pragma unroll
            for (int j = 0; j < 8; ++j) {
                unsigned q = __builtin_amdgcn_readlane(rec, i + j);
                v[j] = __uint_as_float((q & 0x7FFFu) << 16);
                g[j] = Gf[(size_t)(q >> 15) * 64];
            }
            #pragma unroll
            for (int j = 0; j < 8; ++j) {
                a0 += v[j] * bf2f((unsigned short)g[j]);
                a1 += v[j] * bf2f((unsigned short)(g[j] >> 16));
            }
        }
        for (; i < take; ++i) {
            unsigned q = __builtin_amdgcn_readlane(rec, i);
            float v = __uint_as_float((q & 0x7FFFu) << 16);
            unsigned g = Gf[(size_t)(q >> 15) * 64];
            a0 += v * bf2f((unsigned short)g);
            a1 += v * bf2f((unsigned short)(g >> 16));
        }
        e0 += take;
    }
    a0 = fmaxf(a0, 0.f); a1 = fmaxf(a1, 0.f);
    Y[(size_t)node * 64 + lane] = (unsigned)f2bf(a0) | ((unsigned)f2bf(a1) << 16);
}

// ---------------- SpMM last: F=64, 8-lane x 16B groups, 8 edges per dwordx4 round, 4B records ----

__global__ __launch_bounds__(256) void spmm_last(const int* __restrict__ rp,
                                                 const unsigned* __restrict__ erec,
                                                 const unsigned short* __restrict__ G,  // [n][64] bf16
                                                 float* __restrict__ out, int n) {
    int node = blockIdx.x * 4 + (threadIdx.x >> 6);
    if (node >= n) return;
    int lane = threadIdx.x & 63;
    int eg = lane >> 3, fg = lane & 7;
    int e0 = rp[node], e1 = rp[node + 1];
    float acc[8] = {0.f, 0.f, 0.f, 0.f, 0.f, 0.f, 0.f, 0.f};
    while (e0 < e1) {
        int take = e1 - e0; if (take > 64) take = 64;
        unsigned rec = erec[e0 + (lane < take ? lane : take - 1)];
        for (int r = 0; r < take; r += 16) {
            uint4 d[2]; float vv[2];
            #pragma unroll
            for (int s = 0; s < 2; ++s) {
                int idx = r + s * 8 + eg;
                bool ok = idx < take;
                int src = ok ? idx : take - 1;
                unsigned q = __shfl(rec, src);
                float v = __uint_as_float((q & 0x7FFFu) << 16);
                vv[s] = ok ? v : 0.f;
                d[s] = *reinterpret_cast<const uint4*>(G + (size_t)(q >> 15) * 64 + fg * 8);
            }
            #pragma unroll
            for (int s = 0; s < 2; ++s) {
                unsigned w0 = d[s].x, w1 = d[s].y, w2 = d[s].z, w3 = d[s].w;
                acc[0] += vv[s] * bf2f((unsigned short)w0);
                acc[1] += vv[s] * bf2f((unsigned short)(w0 >> 16));
                acc[2] += vv[s] * bf2f((unsigned short)w1);
                acc[3] += vv[s] * bf2f((unsigned short)(w1 >> 16));
                acc[4] += vv[s] * bf2f((unsigned short)w2);
                acc[5] += vv[s] * bf2f((unsigned short)(w2 >> 16));
                acc[6] += vv[s] * bf2f((unsigned short)w3);
                acc[7] += vv[s] * bf2f((unsigned short)(w3 >> 16));
            }
        }
        e0 += take;
    }
    #pragma unroll
    for (int k = 0; k < 8; ++k) {
        acc[k] += __shfl_xor(acc[k], 8);
        acc[k] += __shfl_xor(acc[k], 16);
        acc[k] += __shfl_xor(acc[k], 32);
    }
    if (eg == 0) {
        float4 oA = {acc[0], acc[1], acc[2], acc[3]};
        float4 oB = {acc[4], acc[5], acc[6], acc[7]};
        float4* o = reinterpret_cast<float4*>(out + (size_t)node * 64 + fg * 8);
        o[0] = oA;
        o[1] = oB;
    }
}

// ---------------- launch ----------------

extern "C" void kernel_launch(void* const* d_in, const int* in_sizes, int n_in,
                              void* d_out, int out_size, void* d_ws, size_t ws_size,
                              hipStream_t stream) {
    const float* x    = (const float*)d_in[0];
    const int*   arow = (const int*)d_in[1];
    const int*   acol = (const int*)d_in[2];
    const float* aval = (const float*)d_in[3];
    const float* W0   = (const float*)d_in[4];
    const float* b0   = (const float*)d_in[5];
    const float* W1   = (const float*)d_in[6];
    const float* b1   = (const float*)d_in[7];
    const float* W2   = (const float*)d_in[8];
    const float* b2   = (const float*)d_in[9];
    float* out = (float*)d_out;

    // workspace layout
    unsigned short* hlin = (unsigned short*)d_ws;                       // N*128 u16
    unsigned short* hact = hlin + (size_t)N_NODES * 128;                // N*128 u16
    unsigned short* Bp0  = hact + (size_t)N_NODES * 128;                // 16384 u16
    unsigned short* Bp1  = Bp0 + 16384;                                 // 16384 u16
    unsigned short* Bp2  = Bp1 + 16384;                                 // 8192 u16
    int* cnt  = (int*)(Bp2 + 8192);                                     // SCAN_N
    int* base = cnt + SCAN_N;                                           // SCAN_N
    int* rp   = base + SCAN_N;                                          // N+2
    int2* bin_in = (int2*)(rp + N_NODES + 2);                           // E int2
    unsigned* erec = (unsigned*)(bin_in + N_EDGES);                     // E u32

    // partition / CSR build, with pack (in p2) and layer-0 GEMM (in p3) overlapped
    p1_bincnt<<<NBLK, 256, 0, stream>>>(arow, cnt);
    p2_scan_pack<<<41, 1024, 0, stream>>>(cnt, base, rp, W0, W1, W2, Bp0, Bp1, Bp2);
    p3_gemm0<<<NBLK + GEMM_BLKS, 256, 0, stream>>>(arow, acol, aval, base, bin_in,
                                                   x, Bp0, b0, hlin, N_NODES);
    p4_binscatter<<<NBIN, 256, 0, stream>>>(base, bin_in, rp, erec);

    int spmm_grid = (N_NODES + 3) / 4;

    // spmm0 (layer-0 GEMM already done inside p3_gemm0)
    spmm_mid<<<spmm_grid, 256, 0, stream>>>(rp, erec, (const unsigned*)hlin, (unsigned*)hact, N_NODES);
    // layer 1
    gemm_mfma<8, false><<<GEMM_BLKS, 256, 0, stream>>>(hact, Bp1, b1, hlin, N_NODES);
    spmm_mid<<<spmm_grid, 256, 0, stream>>>(rp, erec, (const unsigned*)hlin, (unsigned*)hact, N_NODES);
    // layer 2
    gemm_mfma<4, false><<<GEMM_BLKS, 256, 0, stream>>>(hact, Bp2, b2, hlin, N_NODES);
    spmm_last<<<spmm_grid, 256, 0, stream>>>(rp, erec, hlin, out, N_NODES);
}